// Round 3
// baseline (105.612 us; speedup 1.0000x reference)
//
#include <hip/hip_runtime.h>
#include <hip/hip_bf16.h>

typedef __attribute__((ext_vector_type(8))) __bf16 bf16x8;
typedef __attribute__((ext_vector_type(4))) float f32x4;
typedef unsigned short u16;
typedef unsigned int u32;

#define NB 8192
#define ND 128
#define NEGINF (-__builtin_inff())
#define POSINF (__builtin_inff())
#define ENC_NEGINF 0x007FFFFFu   // encf(-inf)
#define ENC_POSINF 0xFF800000u   // encf(+inf)

__device__ inline u16 f2b(float f){
  __hip_bfloat16 h = __float2bfloat16(f);
  return *reinterpret_cast<u16*>(&h);
}
// monotone float <-> uint encoding (order-preserving, incl. +-inf)
__device__ inline u32 encf(float f){
  u32 b = __float_as_uint(f);
  return b ^ (0x80000000u | (u32)(((int)b) >> 31));
}
__device__ inline float decf(u32 u){
  return __uint_as_float(u ^ (0x80000000u | (u32)((~(int)u) >> 31)));
}

// ---- prep: fp32->bf16, colp=(sq, p, sq*p, lab), init atomic targets --------
extern "C" __global__ __launch_bounds__(256)
void prep_k(const float* __restrict__ x, const int* __restrict__ lab,
            u16* __restrict__ xb, float4* __restrict__ colp,
            u32* __restrict__ ppos, u32* __restrict__ pneg)
{
  const int tid = blockIdx.x * 256 + threadIdx.x;
  const int row = tid >> 5;
  const int sub = tid & 31;
  const float4 v = reinterpret_cast<const float4*>(x)[row * 32 + sub];
  float s = v.x*v.x + v.y*v.y + v.z*v.z + v.w*v.w;
  #pragma unroll
  for (int m = 1; m < 32; m <<= 1) s += __shfl_xor(s, m, 32);
  ushort4 o;
  o.x = f2b(v.x); o.y = f2b(v.y); o.z = f2b(v.z); o.w = f2b(v.w);
  reinterpret_cast<ushort4*>(xb)[row * 32 + sub] = o;
  if (sub == 0){
    const float p = 1.0f / (1.0f - s);
    colp[row] = make_float4(s, p, s * p, __int_as_float(lab[row]));
  }
  if (sub == 1) ppos[row] = ENC_NEGINF;
  if (sub == 2) pneg[row] = ENC_POSINF;
}

// ---- main: symmetric (upper-triangle) 128x128 tiles -------------------------
// 2080 blocks; block (bi<=bj): rows tile bi, cols tile bj. 4 waves x 32 rows.
// Each Gram entry yields row update (u=d2*p_j) and, if bi!=bj, col update
// (u=d2*p_i). Cross-block merge via device-scope atomics on encoded floats.
extern "C" __global__ __launch_bounds__(256, 2)
void gram_k(const u16* __restrict__ xb, const float4* __restrict__ colp,
            u32* __restrict__ ppos, u32* __restrict__ pneg)
{
  __shared__ u16 Bt[128 * 128];   // 32 KB; 256B/row, 16B chunks XOR-swizzled by row&15
  const int wid  = threadIdx.x >> 6;
  const int lane = threadIdx.x & 63;
  const int m16  = lane & 15;
  const int quad = lane >> 4;

  // triangular decode (block-uniform): g(b)=b*(129-b)/2
  int idx = (int)blockIdx.x;
  int bi = (int)((129.0f - sqrtf((float)(16641 - 8 * idx))) * 0.5f);
  while ((bi + 1) * (129 - (bi + 1)) / 2 <= idx) ++bi;
  while (bi * (129 - bi) / 2 > idx) --bi;
  const int bj = bi + (idx - bi * (129 - bi) / 2);
  const bool diag = (bi == bj);
  const int C0  = bj * 128;
  const int WR0 = bi * 128 + wid * 32;

  // stage B tile (cols = rows of tile bj): LDS chunk p of row j <- global chunk p^(j&15)
  #pragma unroll
  for (int c = 0; c < 8; ++c){
    const int cc   = wid * 8 + c;
    const int brow = cc * 4 + quad;
    const int src  = m16 ^ (brow & 15);
    const u16* gsrc = xb + (C0 + brow) * ND + src * 8;
    __builtin_amdgcn_global_load_lds(
        (const __attribute__((address_space(1))) void*)gsrc,
        (__attribute__((address_space(3))) void*)(Bt + cc * 512), 16, 0, 0);
  }

  // A fragments in registers (overlaps with staging): A[m=lane&15][k=quad*8+j]
  bf16x8 afrag[2][4];
  #pragma unroll
  for (int mt = 0; mt < 2; ++mt){
    const u16* arow = xb + (WR0 + mt*16 + m16) * ND;
    #pragma unroll
    for (int ks = 0; ks < 4; ++ks)
      afrag[mt][ks] = *reinterpret_cast<const bf16x8*>(arow + ks*32 + quad*8);
  }

  // per-row params (C/D row = quad*4 + r)
  float sqi[8], pi[8]; int labi[8];
  #pragma unroll
  for (int mt = 0; mt < 2; ++mt)
    #pragma unroll
    for (int r = 0; r < 4; ++r){
      const float4 cp = colp[WR0 + mt*16 + quad*4 + r];
      sqi[mt*4+r]  = cp.x;
      pi[mt*4+r]   = cp.y;
      labi[mt*4+r] = __float_as_int(cp.w);
    }

  __syncthreads();

  f32x4 acc[2][8];
  #pragma unroll
  for (int mt = 0; mt < 2; ++mt)
    #pragma unroll
    for (int nt = 0; nt < 8; ++nt){
      f32x4 z = {0.f, 0.f, 0.f, 0.f};
      acc[mt][nt] = z;
    }

  #pragma unroll
  for (int ks = 0; ks < 4; ++ks){
    const int t = ks * 4 + quad;
    #pragma unroll
    for (int nt = 0; nt < 8; ++nt){
      const bf16x8 bfrag = *reinterpret_cast<const bf16x8*>(
          Bt + (nt*16 + m16) * 128 + ((t ^ m16) * 8));
      acc[0][nt] = __builtin_amdgcn_mfma_f32_16x16x32_bf16(afrag[0][ks], bfrag, acc[0][nt], 0, 0, 0);
      acc[1][nt] = __builtin_amdgcn_mfma_f32_16x16x32_bf16(afrag[1][ks], bfrag, acc[1][nt], 0, 0, 0);
    }
  }

  float vpos[8], vneg[8], cpos[8], cneg[8];
  #pragma unroll
  for (int i = 0; i < 8; ++i){
    vpos[i] = NEGINF; vneg[i] = POSINF;
    cpos[i] = NEGINF; cneg[i] = POSINF;
  }

  if (!diag){
    #pragma unroll
    for (int nt = 0; nt < 8; ++nt){
      const float4 cp = colp[C0 + nt*16 + m16];
      const float sqj  = cp.x;
      const float pj   = cp.y;
      const int   labj = __float_as_int(cp.w);
      #pragma unroll
      for (int mt = 0; mt < 2; ++mt)
        #pragma unroll
        for (int r = 0; r < 4; ++r){
          const int i = mt*4 + r;
          const float d2 = fmaf(-2.0f, acc[mt][nt][r], sqi[i] + sqj);
          const float ur = d2 * pj;
          const float uc = d2 * pi[i];
          const bool sm = (labi[i] == labj);
          vpos[i]  = fmaxf(vpos[i],  sm ? ur : NEGINF);
          vneg[i]  = fminf(vneg[i],  sm ? POSINF : ur);
          cpos[nt] = fmaxf(cpos[nt], sm ? uc : NEGINF);
          cneg[nt] = fminf(cneg[nt], sm ? POSINF : uc);
        }
    }
  } else {
    // diagonal block: row updates only (covers all pairs); exclude self
    #pragma unroll
    for (int nt = 0; nt < 8; ++nt){
      const float4 cp = colp[C0 + nt*16 + m16];
      const float sqj  = cp.x;
      const float pj   = cp.y;
      const int   labj = __float_as_int(cp.w);
      const int colin  = nt*16 + m16;
      #pragma unroll
      for (int mt = 0; mt < 2; ++mt)
        #pragma unroll
        for (int r = 0; r < 4; ++r){
          const int i = mt*4 + r;
          const float d2 = fmaf(-2.0f, acc[mt][nt][r], sqi[i] + sqj);
          const float ur = d2 * pj;
          const bool sm = (labi[i] == labj);
          const bool dg = (colin == wid*32 + mt*16 + quad*4 + r);
          float ep = sm ? ur : NEGINF;
          ep = dg ? NEGINF : ep;
          vpos[i] = fmaxf(vpos[i], ep);
          vneg[i] = fminf(vneg[i], sm ? POSINF : ur);
        }
    }
  }

  // row states: reduce across the 16 col-lanes, then atomic merge
  #pragma unroll
  for (int i = 0; i < 8; ++i){
    #pragma unroll
    for (int m = 1; m < 16; m <<= 1){
      vpos[i] = fmaxf(vpos[i], __shfl_xor(vpos[i], m, 16));
      vneg[i] = fminf(vneg[i], __shfl_xor(vneg[i], m, 16));
    }
  }
  if (m16 == 0){
    #pragma unroll
    for (int i = 0; i < 8; ++i){
      const int row = WR0 + (i >> 2)*16 + quad*4 + (i & 3);
      atomicMax(ppos + row, encf(vpos[i]));
      atomicMin(pneg + row, encf(vneg[i]));
    }
  }

  if (!diag){
    // col states: reduce across quads (rows), merge waves via LDS, then atomics
    #pragma unroll
    for (int nt = 0; nt < 8; ++nt){
      cpos[nt] = fmaxf(cpos[nt], __shfl_xor(cpos[nt], 16));
      cpos[nt] = fmaxf(cpos[nt], __shfl_xor(cpos[nt], 32));
      cneg[nt] = fminf(cneg[nt], __shfl_xor(cneg[nt], 16));
      cneg[nt] = fminf(cneg[nt], __shfl_xor(cneg[nt], 32));
    }
    float* cbP = reinterpret_cast<float*>(Bt);        // 4x128 floats
    float* cbN = cbP + 512;                            // 4x128 floats
    __syncthreads();   // all ds_reads of Bt done; safe to reuse
    if (quad == 0){
      #pragma unroll
      for (int nt = 0; nt < 8; ++nt){
        cbP[wid*128 + nt*16 + m16] = cpos[nt];
        cbN[wid*128 + nt*16 + m16] = cneg[nt];
      }
    }
    __syncthreads();
    if (threadIdx.x < 128){
      const int c = threadIdx.x;
      float P = NEGINF, N = POSINF;
      #pragma unroll
      for (int w = 0; w < 4; ++w){
        P = fmaxf(P, cbP[w*128 + c]);
        N = fminf(N, cbN[w*128 + c]);
      }
      atomicMax(ppos + C0 + c, encf(P));
      atomicMin(pneg + C0 + c, encf(N));
    }
  }
}

// ---- finalize stage 1: 64 blocks x 128 rows -> per-block (sum, cnt) --------
extern "C" __global__ __launch_bounds__(128)
void fin1_k(const u32* __restrict__ ppos, const u32* __restrict__ pneg,
            const float4* __restrict__ colp, float2* __restrict__ bpart)
{
  const int row = blockIdx.x * 128 + threadIdx.x;
  const float up = decf(ppos[row]);
  const float un = decf(pneg[row]);
  const bool hp = (up > NEGINF);
  const bool hn = (un < POSINF);
  const float pr = colp[row].y;
  float dp = 0.0f, dn = 0.0f;
  // arccosh(1+t) = log1p(t + sqrt(t*(t+2))), t clamped at 1e-7 (matches ref)
  if (hp){ float t = fmaxf(2.0f * up * pr, 1e-7f); dp = log1pf(t + sqrtf(t * (t + 2.0f))); }
  if (hn){ float t = fmaxf(2.0f * un * pr, 1e-7f); dn = log1pf(t + sqrtf(t * (t + 2.0f))); }
  float lsum = (hp && hn) ? fmaxf(dp - dn + 0.5f, 0.0f) : 0.0f;
  float lcnt = (hp && hn) ? 1.0f : 0.0f;
  #pragma unroll
  for (int m = 1; m < 64; m <<= 1){
    lsum += __shfl_xor(lsum, m, 64);
    lcnt += __shfl_xor(lcnt, m, 64);
  }
  __shared__ float2 s_p[2];
  if ((threadIdx.x & 63) == 0) s_p[threadIdx.x >> 6] = make_float2(lsum, lcnt);
  __syncthreads();
  if (threadIdx.x == 0)
    bpart[blockIdx.x] = make_float2(s_p[0].x + s_p[1].x, s_p[0].y + s_p[1].y);
}

// ---- finalize stage 2: one wave reduces 64 partials ------------------------
extern "C" __global__ __launch_bounds__(64)
void fin2_k(const float2* __restrict__ bpart, float* __restrict__ out)
{
  float2 p = bpart[threadIdx.x];
  float s = p.x, c = p.y;
  #pragma unroll
  for (int m = 1; m < 64; m <<= 1){
    s += __shfl_xor(s, m, 64);
    c += __shfl_xor(c, m, 64);
  }
  if (threadIdx.x == 0) out[0] = (c > 0.0f) ? (s / c) : 0.0f;
}

extern "C" void kernel_launch(void* const* d_in, const int* in_sizes, int n_in,
                              void* d_out, int out_size, void* d_ws, size_t ws_size,
                              hipStream_t stream)
{
  const float* x  = (const float*)d_in[0];
  const int* lab  = (const int*)d_in[1];
  char* ws = (char*)d_ws;
  u16*    xb   = (u16*)ws;                                   // 2 MB
  float4* colp = (float4*)(ws + (size_t)2*1024*1024);        // 128 KB
  u32*    ppos = (u32*)(ws + (size_t)2*1024*1024 + 128*1024);          // 32 KB
  u32*    pneg = (u32*)(ws + (size_t)2*1024*1024 + 160*1024);          // 32 KB
  float2* bpart= (float2*)(ws + (size_t)2*1024*1024 + 192*1024);       // 512 B

  hipLaunchKernelGGL(prep_k, dim3(1024), dim3(256), 0, stream, x, lab, xb, colp, ppos, pneg);
  hipLaunchKernelGGL(gram_k, dim3(2080), dim3(256), 0, stream, xb, colp, ppos, pneg);
  hipLaunchKernelGGL(fin1_k, dim3(64), dim3(128), 0, stream, ppos, pneg, colp, bpart);
  hipLaunchKernelGGL(fin2_k, dim3(1), dim3(64), 0, stream, bpart, (float*)d_out);
}